// Round 1
// baseline (1430.660 us; speedup 1.0000x reference)
//
#include <hip/hip_runtime.h>

// Problem constants (from reference)
#define VOCAB 32000
#define NNZ   801
#define NROWS 8192            // B*T = 4*2048
#define THREADS 512           // 8 waves per block

// Each row's 128KB logp slice is staged by TWO blocks, 64KB each:
//   half 0 stages floats [0, 16384)            and owns gathers with c <  16000
//   half 1 stages floats [15616, 32000)        and owns gathers with c >= 16000
// (both windows are exactly 16384 floats = 64KB; they overlap by 768 floats,
//  and the ownership split point 16000 lies inside the overlap)
#define HALF_FLOATS 16384
#define HALF1_BASE  (VOCAB - HALF_FLOATS)   // 15616
#define SPLIT       16000

// partials layout (doubles) in workspace
#define GV_OFF 0                 // [2*NROWS]  per (row,half) sum(val*g) over owned cols
#define SV_OFF (2*NROWS)         // [NROWS]    sum(val) over all j   (written by half 0)
#define ML_OFF (3*NROWS)         // [2*NROWS]  -lp[trow]*m from owning half, 0 from other
#define MV_OFF (5*NROWS)         // [NROWS]    mask (written by half 0)
// total: 6*NROWS doubles = 384 KB << ws

typedef const __attribute__((address_space(1))) unsigned int* gaddr_t;
typedef __attribute__((address_space(3))) unsigned int* laddr_t;

__device__ __forceinline__ float wave_reduce_add_f(float v) {
    #pragma unroll
    for (int off = 32; off > 0; off >>= 1) v += __shfl_down(v, off, 64);
    return v;
}

__global__ __launch_bounds__(THREADS) void wordsmooth_main(
        const float* __restrict__ logp,        // [NROWS, VOCAB]
        const float* __restrict__ mask,        // [NROWS]
        const float* __restrict__ sim_values,  // [VOCAB, NNZ]
        const float* __restrict__ idf_values,  // [VOCAB, NNZ]
        const int*   __restrict__ target,      // [NROWS]
        const int*   __restrict__ sim_cols,    // [VOCAB, NNZ]
        double*      __restrict__ partials)
{
    __shared__ float lds[HALF_FLOATS];         // exactly 64 KB -> 2 blocks/CU

    const int tid  = threadIdx.x;
    const int lane = tid & 63;
    const int wave = tid >> 6;                 // 0..7
    const int row  = blockIdx.x >> 1;
    const int half = blockIdx.x & 1;
    const int base = half ? HALF1_BASE : 0;

    const int trow = target[row];
    const float* __restrict__ sv_p = sim_values + (size_t)trow * NNZ;
    const float* __restrict__ iv_p = idf_values + (size_t)trow * NNZ;
    const int*   __restrict__ sc_p = sim_cols   + (size_t)trow * NNZ;
    const float* __restrict__ grow = logp + (size_t)row * VOCAB + base;

    // ---- issue the streaming (sv/iv/sc) loads first so the val computation
    //      only waits on them (vmcnt counted in-order), leaving the staging
    //      loads in flight until the barrier drain ----
    const float TAU_INV  = 1.25f;   // 1/0.8
    const float TAU_RARE = 0.8f;    // TAU*RARE

    float sv0 = sv_p[tid];
    float iv0 = iv_p[tid];
    int   c0  = sc_p[tid];
    const bool has1 = (tid < (NNZ - THREADS));   // tid < 289
    float sv1 = 0.0f, iv1 = 0.0f; int c1 = 0;
    if (has1) { sv1 = sv_p[tid + THREADS]; iv1 = iv_p[tid + THREADS]; c1 = sc_p[tid + THREADS]; }

    // ---- async stage this 64KB logp half-row into LDS (width-16 direct-to-LDS).
    //      wave w owns floats [w*2048,(w+1)*2048); per round a wave writes
    //      lds_base + lane*16 -- matches the per-lane global source exactly ----
    #pragma unroll
    for (int r = 0; r < 8; ++r) {
        const int foff = wave * 2048 + r * 256;            // wave-uniform float offset
        __builtin_amdgcn_global_load_lds(
            (gaddr_t)(grow + foff + lane * 4),
            (laddr_t)(lds + foff), 16, 0, 0);
    }

    // ---- val computation (independent of LDS contents) ----
    float x0 = (sv0 - 1.0f - TAU_RARE * iv0) * TAU_INV;
    float v0 = __expf(__expf(x0) * TAU_INV);
    float v1 = 0.0f;
    if (has1) {
        float x1 = (sv1 - 1.0f - TAU_RARE * iv1) * TAU_INV;
        v1 = __expf(__expf(x1) * TAU_INV);
    }
    float s_v = v0 + v1;            // only half 0's copy is used downstream

    __syncthreads();                // drains vmcnt(0): staging complete

    // ---- gathers are now LDS-local ----
    float s_gv = 0.0f;
    const bool mine0 = half ? (c0 >= SPLIT) : (c0 < SPLIT);
    if (mine0) s_gv += v0 * lds[c0 - base];
    if (has1) {
        const bool mine1 = half ? (c1 >= SPLIT) : (c1 < SPLIT);
        if (mine1) s_gv += v1 * lds[c1 - base];
    }

    // ml term: the half that owns trow reads lp[trow] from LDS
    float lp_t = 0.0f;
    const bool own_ml = half ? (trow >= SPLIT) : (trow < SPLIT);
    if (tid == 0 && own_ml) lp_t = lds[trow - base];

    // ---- block reduction (reuse lds scratch after all reads are done) ----
    s_v  = wave_reduce_add_f(s_v);
    s_gv = wave_reduce_add_f(s_gv);
    __syncthreads();                // all LDS gather reads retired
    if (lane == 0) { lds[wave] = s_gv; lds[8 + wave] = s_v; }
    __syncthreads();
    if (tid == 0) {
        float gv = 0.0f, vv = 0.0f;
        #pragma unroll
        for (int w = 0; w < 8; ++w) { gv += lds[w]; vv += lds[8 + w]; }
        const float m = mask[row];
        partials[GV_OFF + 2 * row + half] = (double)gv;
        partials[ML_OFF + 2 * row + half] = own_ml ? (double)(-lp_t * m) : 0.0;
        if (!half) {
            partials[SV_OFF + row] = (double)vv;
            partials[MV_OFF + row] = (double)m;
        }
    }
}

__global__ __launch_bounds__(256) void wordsmooth_finalize(
        const double* __restrict__ partials, float* __restrict__ out)
{
    double sm = 0.0, ml = 0.0, dn = 0.0;
    for (int r = threadIdx.x; r < NROWS; r += 256) {
        double gv = partials[GV_OFF + 2 * r] + partials[GV_OFF + 2 * r + 1];
        double sv = partials[SV_OFF + r];
        sm += -gv / sv;                                   // smooth partial (no mask)
        ml += partials[ML_OFF + 2 * r] + partials[ML_OFF + 2 * r + 1];
        dn += partials[MV_OFF + r];
    }
    #pragma unroll
    for (int off = 32; off > 0; off >>= 1) {
        sm += __shfl_down(sm, off, 64);
        ml += __shfl_down(ml, off, 64);
        dn += __shfl_down(dn, off, 64);
    }
    __shared__ double sh[3][4];
    const int lane = threadIdx.x & 63;
    const int wave = threadIdx.x >> 6;
    if (lane == 0) { sh[0][wave] = sm; sh[1][wave] = ml; sh[2][wave] = dn; }
    __syncthreads();
    if (threadIdx.x == 0) {
        double S = 0.0, M = 0.0, D = 0.0;
        #pragma unroll
        for (int w = 0; w < 4; ++w) { S += sh[0][w]; M += sh[1][w]; D += sh[2][w]; }
        const double ALPHA = 0.7;
        out[0] = (float)((ALPHA * S + (1.0 - ALPHA) * M) / D);
    }
}

extern "C" void kernel_launch(void* const* d_in, const int* in_sizes, int n_in,
                              void* d_out, int out_size, void* d_ws, size_t ws_size,
                              hipStream_t stream) {
    const float* logp       = (const float*)d_in[0];
    const float* mask       = (const float*)d_in[1];
    const float* sim_values = (const float*)d_in[2];
    const float* idf_values = (const float*)d_in[3];
    const int*   target     = (const int*)d_in[4];
    const int*   sim_cols   = (const int*)d_in[5];
    float* out = (float*)d_out;
    double* partials = (double*)d_ws;   // 6*NROWS doubles, fully overwritten each run

    dim3 grid(2 * NROWS);   // 16384 half-row blocks
    dim3 block(THREADS);
    wordsmooth_main<<<grid, block, 0, stream>>>(logp, mask, sim_values, idf_values,
                                                target, sim_cols, partials);
    wordsmooth_finalize<<<1, 256, 0, stream>>>(partials, out);
}